// Round 2
// baseline (297.886 us; speedup 1.0000x reference)
//
#include <hip/hip_runtime.h>
#include <hip/hip_bf16.h>

typedef short s16x4 __attribute__((ext_vector_type(4)));
typedef short s16x8 __attribute__((ext_vector_type(8)));
typedef float f32x4 __attribute__((ext_vector_type(4)));
typedef float f32x16 __attribute__((ext_vector_type(16)));

#define NB 2
#define NSEQ 2048
#define NHID 896
#define NHQ 14
#define NHKV 2
#define HD 64
#define NROW (NB*NSEQ)     // 4096
#define NCAT 2048          // 896 Q | 128 K | 128 V | 896 gate

__device__ __forceinline__ float bf2f(unsigned short s){
  union { float f; unsigned u; } v; v.u = ((unsigned)s) << 16; return v.f;
}
__device__ __forceinline__ short f2bf(float f){
  union { float f; unsigned u; } v; v.f = f;
  unsigned u = v.u + 0x7fffu + ((v.u >> 16) & 1u);
  return (short)(u >> 16);
}

// ---------------- packing kernels ----------------

__global__ void pack_x_kernel(const float* __restrict__ x, short* __restrict__ xb, int n){
  int i = blockIdx.x*256 + threadIdx.x;
  if(i < n) xb[i] = f2bf(x[i]);
}

// WcatT[c][k] = W(k, c) for concatenated [Wq|Wk|Wv|Wg] columns, bf16
__global__ void pack_wcat_kernel(const float* __restrict__ Wq, const float* __restrict__ Wk,
                                 const float* __restrict__ Wv, const float* __restrict__ Wg,
                                 short* __restrict__ WcatT){
  int t = blockIdx.x*256 + threadIdx.x;
  if(t >= NCAT*NHID) return;
  int k = t % NHID, c = t / NHID;
  float v;
  if(c < 896)       v = Wq[k*896 + c];
  else if(c < 1024) v = Wk[k*128 + (c-896)];
  else if(c < 1152) v = Wv[k*128 + (c-1024)];
  else              v = Wg[k*896 + (c-1152)];
  WcatT[t] = f2bf(v);
}

__global__ void pack_wo_kernel(const float* __restrict__ Wo, short* __restrict__ WoT){
  int t = blockIdx.x*256 + threadIdx.x;
  if(t >= NHID*NHID) return;
  int k = t % NHID, c = t / NHID;
  WoT[t] = f2bf(Wo[k*896 + c]);
}

__global__ void rope_table_kernel(const int* __restrict__ pos, float* __restrict__ ct,
                                  float* __restrict__ st){
  int t = blockIdx.x*256 + threadIdx.x;
  if(t >= NROW*32) return;
  int i = t & 31, rn = t >> 5;
  float p = (float)pos[rn];
  float inv = powf(1.0e6f, -(float)i * (1.0f/32.0f));
  float a = p * inv;
  ct[t] = cosf(a);
  st[t] = sinf(a);
}

// V [bh][n][d] -> VbT [bh][d][n]  (LDS tiled transpose, bf16)
__global__ __launch_bounds__(256) void transpose_v_kernel(const short* __restrict__ Vb,
                                                          short* __restrict__ VbT){
  __shared__ short t[64][66];
  int bh = blockIdx.y;           // 0..3
  int n0 = blockIdx.x * 64;      // 32 tiles
  int tid = threadIdx.x;
  #pragma unroll
  for(int it=0; it<2; ++it){
    int idx = it*256 + tid;
    int r = idx >> 3, c0 = (idx & 7)*8;
    s16x8 v = *(const s16x8*)(Vb + ((long)bh*NSEQ + n0 + r)*HD + c0);
    #pragma unroll
    for(int e=0;e<8;e++) t[r][c0+e] = v[e];
  }
  __syncthreads();
  #pragma unroll
  for(int it=0; it<2; ++it){
    int idx = it*256 + tid;
    int d = idx >> 3, k0 = (idx & 7)*8;
    s16x8 o;
    #pragma unroll
    for(int e=0;e<8;e++) o[e] = t[k0+e][d];
    *(s16x8*)(VbT + ((long)bh*HD + d)*NSEQ + n0 + k0) = o;
  }
}

// ---------------- GEMM (bf16 MFMA, LDS double-buffer via global_load_lds) ----------------
// EPI=0: QKVG epilogue, EPI=1: plain f32 out

template<int EPI>
__global__ __launch_bounds__(256)
void gemm_kernel(const short* __restrict__ A, const short* __restrict__ Bt,
                 int Ncols, int K,
                 const float* __restrict__ bq, const float* __restrict__ bk,
                 const float* __restrict__ bv,
                 const float* __restrict__ ct, const float* __restrict__ st,
                 short* __restrict__ Qb, short* __restrict__ Kb, short* __restrict__ Vb,
                 short* __restrict__ gateb, float* __restrict__ outp)
{
  __shared__ short As[2][4096];   // [buf][128 rows x 32 k], linear for global_load_lds
  __shared__ short Bs[2][4096];

  int tid = threadIdx.x;
  int w = tid >> 6, l = tid & 63;
  int wm = w >> 1, wn = w & 1;
  int row0 = blockIdx.y*128;
  int col0 = blockIdx.x*128;
  int lo = l & 15, hi = l >> 4;

  const short* A0 = A  + (long)row0*K;
  const short* B0 = Bt + (long)col0*K;

  f32x4 acc[4][4];
  #pragma unroll
  for(int mi=0;mi<4;mi++)
    #pragma unroll
    for(int ni=0;ni<4;ni++) acc[mi][ni] = (f32x4){0.f,0.f,0.f,0.f};

  auto stage = [&](int buf, int k0){
    #pragma unroll
    for(int it=0; it<2; ++it){
      int ob = it*4096 + w*1024;     // wave-uniform dest byte base within 8KB buffer
      int o  = ob + l*16;            // this lane's dest byte (HW appends lane*16)
      int rr = o >> 6;               // row (64B rows)
      int cc = (o >> 4) & 3;         // 16B chunk in row
      __builtin_amdgcn_global_load_lds(
        (const __attribute__((address_space(1))) void*)(A0 + (long)rr*K + k0 + 8*cc),
        (__attribute__((address_space(3))) void*)((char*)&As[buf][0] + ob), 16, 0, 0);
      __builtin_amdgcn_global_load_lds(
        (const __attribute__((address_space(1))) void*)(B0 + (long)rr*K + k0 + 8*cc),
        (__attribute__((address_space(3))) void*)((char*)&Bs[buf][0] + ob), 16, 0, 0);
    }
  };

  stage(0, 0);
  __syncthreads();

  for(int k0=0; k0<K; k0+=32){
    int buf = (k0 >> 5) & 1;
    if(k0 + 32 < K) stage(buf^1, k0+32);

    s16x8 af[4], bf[4];
    #pragma unroll
    for(int mi=0;mi<4;mi++) af[mi] = *(const s16x8*)&As[buf][(wm*64 + 16*mi + lo)*32 + 8*hi];
    #pragma unroll
    for(int ni=0;ni<4;ni++) bf[ni] = *(const s16x8*)&Bs[buf][(wn*64 + 16*ni + lo)*32 + 8*hi];
    #pragma unroll
    for(int mi=0;mi<4;mi++)
      #pragma unroll
      for(int ni=0;ni<4;ni++)
        acc[mi][ni] = __builtin_amdgcn_mfma_f32_16x16x32_bf16(af[mi], bf[ni], acc[mi][ni], 0,0,0);

    __syncthreads();   // drains vmcnt -> next buffer staged; all reads of cur done
  }

  if(EPI == 1){
    #pragma unroll
    for(int mi=0;mi<4;mi++)
      #pragma unroll
      for(int ni=0;ni<4;ni++)
        #pragma unroll
        for(int rg=0;rg<4;rg++){
          int r = row0 + wm*64 + 16*mi + 4*hi + rg;
          int c = col0 + wn*64 + lo + 16*ni;
          outp[(long)r*Ncols + c] = acc[mi][ni][rg];
        }
  } else {
    int wcol0 = col0 + wn*64;
    int region = (wcol0 < 896) ? 0 : (wcol0 < 1024) ? 1 : (wcol0 < 1152) ? 2 : 3;
    for(int mi=0;mi<4;mi++){
      for(int rg=0;rg<4;rg++){
        int r = row0 + wm*64 + 16*mi + 4*hi + rg;
        int b = r >> 11, n = r & 2047;
        if(region <= 1){
          // RoPE pair: acc[][ni] (d<32) with acc[][ni+2] (d+32), same head
          #pragma unroll
          for(int ni=0;ni<2;ni++){
            int c  = wcol0 + lo + 16*ni;
            int cb = (region==0) ? c : (c-896);
            int hh = cb >> 6, dlo = cb & 63;           // dlo < 32
            float bl = (region==0) ? bq[c]    : bk[cb];
            float bh = (region==0) ? bq[c+32] : bk[cb+32];
            float ylo = acc[mi][ni  ][rg] + bl;
            float yhi = acc[mi][ni+2][rg] + bh;
            float cs = ct[r*32 + dlo];
            float sn = st[r*32 + dlo];
            float olo = ylo*cs - yhi*sn;
            float ohi = yhi*cs + ylo*sn;
            if(region==0){
              long base = ((long)(b*NHQ + hh)*NSEQ + n)*HD;
              Qb[base + dlo]      = f2bf(olo);
              Qb[base + dlo + 32] = f2bf(ohi);
            } else {
              long base = ((long)(b*NHKV + hh)*NSEQ + n)*HD;
              Kb[base + dlo]      = f2bf(olo);
              Kb[base + dlo + 32] = f2bf(ohi);
            }
          }
        } else if(region == 2){
          #pragma unroll
          for(int ni=0;ni<4;ni++){
            int c = wcol0 + lo + 16*ni;
            int cv = c - 1024;
            int hh = cv >> 6, d = cv & 63;
            float y = acc[mi][ni][rg] + bv[cv];
            Vb[((long)(b*NHKV + hh)*NSEQ + n)*HD + d] = f2bf(y);
          }
        } else {
          #pragma unroll
          for(int ni=0;ni<4;ni++){
            int c = wcol0 + lo + 16*ni;
            int cg = c - 1152;
            float y = acc[mi][ni][rg];
            gateb[(long)r*NHID + cg] = f2bf(1.0f/(1.0f + __expf(-y)));
          }
        }
      }
    }
  }
}

// ---------------- fused causal GQA flash attention ----------------
// 1 wave / block, 32 q-rows / wave, 32x32x16 MFMA, zero LDS, zero barriers.
// Swapped QK^T: S^T = mfma(K, Q) -> col = q (lane&31), row = key (lane-local).
// PV uses a key-permutation applied to BOTH V^T A-frag addresses and P B-frags
// so P B-frags are pure in-register packs of the softmax output.

__global__ __launch_bounds__(64)
void attn2_kernel(const short* __restrict__ Qb, const short* __restrict__ Kb,
                  const short* __restrict__ VbT, const short* __restrict__ gateb,
                  short* __restrict__ Og)
{
  const float SC = 0.18033688011112042f;   // (1/8) * log2(e)
  int tid = threadIdx.x;
  int q5 = tid & 31, h = tid >> 5;

  // schedule: tt-major (t descending), 7 heads of same (b,kv,t) adjacent
  int bid = blockIdx.x;
  int hg = bid % 7;
  int rr = bid / 7;
  int bk = rr & 3;
  int tt = rr >> 2;
  int t  = 63 - tt;                 // 32-row q tile, large t first
  int b  = bk >> 1, kv = bk & 1;
  int hq = kv*7 + hg;
  int qg = t*32 + q5;

  const short* qrow = Qb + ((long)(b*NHQ + hq)*NSEQ + t*32 + q5)*HD;
  s16x8 qf[4];
  #pragma unroll
  for(int ks=0; ks<4; ++ks) qf[ks] = *(const s16x8*)(qrow + 16*ks + 8*h);

  const short* kbase = Kb  + (long)(b*NHKV + kv)*NSEQ*HD;
  const short* vbase = VbT + (long)(b*NHKV + kv)*HD*NSEQ;

  f32x16 oT[2];
  #pragma unroll
  for(int mt=0; mt<2; ++mt)
    #pragma unroll
    for(int rg=0; rg<16; ++rg) oT[mt][rg] = 0.f;
  float m = -__builtin_inff(), lsum = 0.f;
  int jmax = (t*32 + 31) >> 6;

  // preload K tile j=0: A-frag rows = key, k = d
  s16x8 kf[2][4];
  #pragma unroll
  for(int kt=0; kt<2; ++kt)
    #pragma unroll
    for(int ks=0; ks<4; ++ks)
      kf[kt][ks] = *(const s16x8*)(kbase + (long)(kt*32 + q5)*HD + 16*ks + 8*h);

  for(int j=0; j<=jmax; ++j){
    // V A-frags (permuted key order): elements e<4 at key 16s+4h+e, e>=4 at +8
    union V8 { s16x8 v8; s16x4 v4[2]; } vf[2][4];
    #pragma unroll
    for(int mt=0; mt<2; ++mt)
      #pragma unroll
      for(int s=0; s<4; ++s){
        const short* vp = vbase + (long)(mt*32 + q5)*NSEQ + j*64 + 16*s + 4*h;
        vf[mt][s].v4[0] = *(const s16x4*)(vp);
        vf[mt][s].v4[1] = *(const s16x4*)(vp + 8);
      }

    // S^T = K * Q^T  (M=key tile of 32, N=q=32, K-dim d=64 in 4 steps)
    f32x16 s2[2];
    #pragma unroll
    for(int kt=0; kt<2; ++kt)
      #pragma unroll
      for(int rg=0; rg<16; ++rg) s2[kt][rg] = 0.f;
    #pragma unroll
    for(int kt=0; kt<2; ++kt)
      #pragma unroll
      for(int ks=0; ks<4; ++ks)
        s2[kt] = __builtin_amdgcn_mfma_f32_32x32x16_bf16(kf[kt][ks], qf[ks], s2[kt], 0,0,0);

    // prefetch next K tile while softmax+PV run
    int jn = (j < jmax) ? j+1 : jmax;
    s16x8 kn[2][4];
    #pragma unroll
    for(int kt=0; kt<2; ++kt)
      #pragma unroll
      for(int ks=0; ks<4; ++ks)
        kn[kt][ks] = *(const s16x8*)(kbase + (long)(jn*64 + kt*32 + q5)*HD + 16*ks + 8*h);

    // scale (+ causal mask on diagonal tile). key row = (rg&3)+8*(rg>>2)+4h
    if(j == jmax){
      #pragma unroll
      for(int kt=0; kt<2; ++kt)
        #pragma unroll
        for(int rg=0; rg<16; ++rg){
          int kl = j*64 + kt*32 + (rg&3) + 8*(rg>>2) + 4*h;
          float sv = s2[kt][rg]*SC;
          s2[kt][rg] = (kl > qg) ? -__builtin_inff() : sv;
        }
    } else {
      #pragma unroll
      for(int kt=0; kt<2; ++kt)
        #pragma unroll
        for(int rg=0; rg<16; ++rg) s2[kt][rg] *= SC;
    }

    // row-max: 32 in-lane (tree) + 1 shuffle across h
    float mA[8];
    #pragma unroll
    for(int w8=0; w8<8; ++w8)
      mA[w8] = fmaxf(fmaxf(s2[0][w8], s2[0][w8+8]), fmaxf(s2[1][w8], s2[1][w8+8]));
    float mx = fmaxf(fmaxf(fmaxf(mA[0],mA[1]), fmaxf(mA[2],mA[3])),
                     fmaxf(fmaxf(mA[4],mA[5]), fmaxf(mA[6],mA[7])));
    mx = fmaxf(mx, __shfl_xor(mx, 32, 64));

    float mn  = fmaxf(m, mx);
    float fac = exp2f(m - mn);
    m = mn;

    // exp + row-sum (tree + 1 shuffle)
    #pragma unroll
    for(int kt=0; kt<2; ++kt)
      #pragma unroll
      for(int rg=0; rg<16; ++rg) s2[kt][rg] = exp2f(s2[kt][rg] - mn);
    float sA[8];
    #pragma unroll
    for(int w8=0; w8<8; ++w8)
      sA[w8] = (s2[0][w8] + s2[0][w8+8]) + (s2[1][w8] + s2[1][w8+8]);
    float rs = ((sA[0]+sA[1]) + (sA[2]+sA[3])) + ((sA[4]+sA[5]) + (sA[6]+sA[7]));
    rs += __shfl_xor(rs, 32, 64);

    lsum = lsum*fac + rs;
    #pragma unroll
    for(int mt=0; mt<2; ++mt)
      #pragma unroll
      for(int rg=0; rg<16; ++rg) oT[mt][rg] *= fac;

    // pack P to bf16 pairs: pd[kt][w] = {p[2w] lo, p[2w+1] hi}
    int pd[2][8];
    #pragma unroll
    for(int kt=0; kt<2; ++kt)
      #pragma unroll
      for(int w8=0; w8<8; ++w8)
        asm("v_cvt_pk_bf16_f32 %0, %1, %2"
            : "=v"(pd[kt][w8]) : "v"(s2[kt][2*w8]), "v"(s2[kt][2*w8+1]));

    // PV: O^T += V^T * P^T ; B-frag for step s = pd[s>>1][4*(s&1) .. +3]
    #pragma unroll
    for(int s=0; s<4; ++s){
      union { int i4[4]; s16x8 v8; } pf;
      #pragma unroll
      for(int e=0; e<4; ++e) pf.i4[e] = pd[s>>1][4*(s&1) + e];
      #pragma unroll
      for(int mt=0; mt<2; ++mt)
        oT[mt] = __builtin_amdgcn_mfma_f32_32x32x16_bf16(vf[mt][s].v8, pf.v8, oT[mt], 0,0,0);
    }

    // roll K prefetch
    #pragma unroll
    for(int kt=0; kt<2; ++kt)
      #pragma unroll
      for(int ks=0; ks<4; ++ks) kf[kt][ks] = kn[kt][ks];
  }

  float inv = 1.0f/lsum;
  long obase = ((long)(b*NSEQ + t*32 + q5))*NHID + hq*HD;
  #pragma unroll
  for(int mt=0; mt<2; ++mt)
    #pragma unroll
    for(int rq=0; rq<4; ++rq){
      int d0 = mt*32 + 8*rq + 4*h;
      s16x4 g4 = *(const s16x4*)(gateb + obase + d0);
      s16x4 o4;
      #pragma unroll
      for(int e=0; e<4; ++e)
        o4[e] = f2bf(oT[mt][4*rq + e]*inv*bf2f((unsigned short)g4[e]));
      *(s16x4*)(Og + obase + d0) = o4;
    }
}

// ---------------- launch ----------------

extern "C" void kernel_launch(void* const* d_in, const int* in_sizes, int n_in,
                              void* d_out, int out_size, void* d_ws, size_t ws_size,
                              hipStream_t stream)
{
  const float* hs  = (const float*)d_in[0];
  const int*   pos = (const int*)d_in[1];
  const float* Wq  = (const float*)d_in[2];
  const float* bq  = (const float*)d_in[3];
  const float* Wk  = (const float*)d_in[4];
  const float* bk  = (const float*)d_in[5];
  const float* Wv  = (const float*)d_in[6];
  const float* bv  = (const float*)d_in[7];
  const float* Wg  = (const float*)d_in[8];
  const float* Wo  = (const float*)d_in[9];
  float* out = (float*)d_out;

  char* p = (char*)d_ws;
  short* Xb    = (short*)p; p += (size_t)NROW*NHID*2;
  short* WcatT = (short*)p; p += (size_t)NCAT*NHID*2;
  short* WoT   = (short*)p; p += (size_t)NHID*NHID*2;
  float* ct    = (float*)p; p += (size_t)NROW*32*4;
  float* st    = (float*)p; p += (size_t)NROW*32*4;
  short* Qb    = (short*)p; p += (size_t)NB*NHQ*NSEQ*HD*2;
  short* Kb    = (short*)p; p += (size_t)NB*NHKV*NSEQ*HD*2;
  short* Vb    = (short*)p; p += (size_t)NB*NHKV*NSEQ*HD*2;
  short* VbT   = (short*)p; p += (size_t)NB*NHKV*NSEQ*HD*2;
  short* gateb = (short*)p; p += (size_t)NROW*NHID*2;
  short* Og    = (short*)p; p += (size_t)NROW*NHID*2;

  pack_x_kernel<<<(NROW*NHID+255)/256, 256, 0, stream>>>(hs, Xb, NROW*NHID);
  pack_wcat_kernel<<<(NCAT*NHID+255)/256, 256, 0, stream>>>(Wq, Wk, Wv, Wg, WcatT);
  pack_wo_kernel<<<(NHID*NHID+255)/256, 256, 0, stream>>>(Wo, WoT);
  rope_table_kernel<<<(NROW*32+255)/256, 256, 0, stream>>>(pos, ct, st);

  gemm_kernel<0><<<dim3(NCAT/128, NROW/128), 256, 0, stream>>>(
      Xb, WcatT, NCAT, NHID, bq, bk, bv, ct, st, Qb, Kb, Vb, gateb, nullptr);

  transpose_v_kernel<<<dim3(NSEQ/64, NB*NHKV), 256, 0, stream>>>(Vb, VbT);

  attn2_kernel<<<64*4*7, 64, 0, stream>>>(Qb, Kb, VbT, gateb, Og);

  gemm_kernel<1><<<dim3(NHID/128, NROW/128), 256, 0, stream>>>(
      Og, WoT, NHID, NHID, nullptr, nullptr, nullptr, nullptr, nullptr,
      nullptr, nullptr, nullptr, nullptr, out);
}

// Round 3
// 285.432 us; speedup vs baseline: 1.0436x; 1.0436x over previous
//
#include <hip/hip_runtime.h>
#include <hip/hip_bf16.h>

typedef short s16x4 __attribute__((ext_vector_type(4)));
typedef short s16x8 __attribute__((ext_vector_type(8)));
typedef float f32x4 __attribute__((ext_vector_type(4)));
typedef float f32x16 __attribute__((ext_vector_type(16)));

#define NB 2
#define NSEQ 2048
#define NHID 896
#define NHQ 14
#define NHKV 2
#define HD 64
#define NROW (NB*NSEQ)     // 4096
#define NCAT 2048          // 896 Q | 128 K | 128 V | 896 gate
#define PS 40              // padded LDS row stride in shorts (80B, 16B-aligned, <=2-way banks)

__device__ __forceinline__ float bf2f(unsigned short s){
  union { float f; unsigned u; } v; v.u = ((unsigned)s) << 16; return v.f;
}
__device__ __forceinline__ short f2bf(float f){
  union { float f; unsigned u; } v; v.f = f;
  unsigned u = v.u + 0x7fffu + ((v.u >> 16) & 1u);
  return (short)(u >> 16);
}

// ---------------- packing kernels ----------------

__global__ void pack_x_kernel(const float* __restrict__ x, short* __restrict__ xb, int n){
  int i = blockIdx.x*256 + threadIdx.x;
  if(i < n) xb[i] = f2bf(x[i]);
}

// WcatT[c][k] = W(k, c) for concatenated [Wq|Wk|Wv|Wg] columns, bf16
__global__ void pack_wcat_kernel(const float* __restrict__ Wq, const float* __restrict__ Wk,
                                 const float* __restrict__ Wv, const float* __restrict__ Wg,
                                 short* __restrict__ WcatT){
  int t = blockIdx.x*256 + threadIdx.x;
  if(t >= NCAT*NHID) return;
  int k = t % NHID, c = t / NHID;
  float v;
  if(c < 896)       v = Wq[k*896 + c];
  else if(c < 1024) v = Wk[k*128 + (c-896)];
  else if(c < 1152) v = Wv[k*128 + (c-1024)];
  else              v = Wg[k*896 + (c-1152)];
  WcatT[t] = f2bf(v);
}

__global__ void pack_wo_kernel(const float* __restrict__ Wo, short* __restrict__ WoT){
  int t = blockIdx.x*256 + threadIdx.x;
  if(t >= NHID*NHID) return;
  int k = t % NHID, c = t / NHID;
  WoT[t] = f2bf(Wo[k*896 + c]);
}

__global__ void rope_table_kernel(const int* __restrict__ pos, float* __restrict__ ct,
                                  float* __restrict__ st){
  int t = blockIdx.x*256 + threadIdx.x;
  if(t >= NROW*32) return;
  int i = t & 31, rn = t >> 5;
  float p = (float)pos[rn];
  float inv = powf(1.0e6f, -(float)i * (1.0f/32.0f));
  float a = p * inv;
  ct[t] = cosf(a);
  st[t] = sinf(a);
}

// V [bh][n][d] -> VbT [bh][d][n]  (LDS tiled transpose, bf16)
__global__ __launch_bounds__(256) void transpose_v_kernel(const short* __restrict__ Vb,
                                                          short* __restrict__ VbT){
  __shared__ short t[64][66];
  int bh = blockIdx.y;           // 0..3
  int n0 = blockIdx.x * 64;      // 32 tiles
  int tid = threadIdx.x;
  #pragma unroll
  for(int it=0; it<2; ++it){
    int idx = it*256 + tid;
    int r = idx >> 3, c0 = (idx & 7)*8;
    s16x8 v = *(const s16x8*)(Vb + ((long)bh*NSEQ + n0 + r)*HD + c0);
    #pragma unroll
    for(int e=0;e<8;e++) t[r][c0+e] = v[e];
  }
  __syncthreads();
  #pragma unroll
  for(int it=0; it<2; ++it){
    int idx = it*256 + tid;
    int d = idx >> 3, k0 = (idx & 7)*8;
    s16x8 o;
    #pragma unroll
    for(int e=0;e<8;e++) o[e] = t[k0+e][d];
    *(s16x8*)(VbT + ((long)bh*HD + d)*NSEQ + n0 + k0) = o;
  }
}

// ---------------- GEMM (bf16 MFMA, reg-staged LDS double-buffer) ----------------
// EPI=0: QKVG epilogue, EPI=1: plain f32 out

template<int EPI>
__global__ __launch_bounds__(256)
void gemm_kernel(const short* __restrict__ A, const short* __restrict__ Bt,
                 int Ncols, int K,
                 const float* __restrict__ bq, const float* __restrict__ bk,
                 const float* __restrict__ bv,
                 const float* __restrict__ ct, const float* __restrict__ st,
                 short* __restrict__ Qb, short* __restrict__ Kb, short* __restrict__ Vb,
                 short* __restrict__ gateb, float* __restrict__ outp)
{
  __shared__ short As[2][128*PS];
  __shared__ short Bs[2][128*PS];

  int tid = threadIdx.x;
  int w = tid >> 6, l = tid & 63;
  int wm = w >> 1, wn = w & 1;
  int row0 = blockIdx.y*128;
  int col0 = blockIdx.x*128;
  int lo = l & 15, hi = l >> 4;

  const short* A0 = A  + (long)row0*K;
  const short* B0 = Bt + (long)col0*K;

  f32x4 acc[4][4];
  #pragma unroll
  for(int mi=0;mi<4;mi++)
    #pragma unroll
    for(int ni=0;ni<4;ni++) acc[mi][ni] = (f32x4){0.f,0.f,0.f,0.f};

  int srow = tid >> 2;          // 0..63
  int scol = (tid & 3)*8;       // 16B chunk within 32-k row

  s16x8 ra[2], rb[2];
  auto gload = [&](int k0){
    #pragma unroll
    for(int i=0;i<2;i++){
      int row = i*64 + srow;
      ra[i] = *(const s16x8*)(A0 + (long)row*K + k0 + scol);
      rb[i] = *(const s16x8*)(B0 + (long)row*K + k0 + scol);
    }
  };
  auto swrite = [&](int buf){
    #pragma unroll
    for(int i=0;i<2;i++){
      int row = i*64 + srow;
      *(s16x8*)&As[buf][row*PS + scol] = ra[i];
      *(s16x8*)&Bs[buf][row*PS + scol] = rb[i];
    }
  };

  gload(0);
  swrite(0);

  int NIT = K >> 5;
  int cur = 0;
  for(int it=0; it<NIT; ++it){
    __syncthreads();
    if(it+1 < NIT) gload((it+1)*32);

    s16x8 af[4], bf[4];
    #pragma unroll
    for(int mi=0;mi<4;mi++) af[mi] = *(const s16x8*)&As[cur][(wm*64 + 16*mi + lo)*PS + 8*hi];
    #pragma unroll
    for(int ni=0;ni<4;ni++) bf[ni] = *(const s16x8*)&Bs[cur][(wn*64 + 16*ni + lo)*PS + 8*hi];
    #pragma unroll
    for(int mi=0;mi<4;mi++)
      #pragma unroll
      for(int ni=0;ni<4;ni++)
        acc[mi][ni] = __builtin_amdgcn_mfma_f32_16x16x32_bf16(af[mi], bf[ni], acc[mi][ni], 0,0,0);

    if(it+1 < NIT) swrite(cur^1);
    cur ^= 1;
  }

  if(EPI == 1){
    #pragma unroll
    for(int mi=0;mi<4;mi++)
      #pragma unroll
      for(int ni=0;ni<4;ni++)
        #pragma unroll
        for(int rg=0;rg<4;rg++){
          int r = row0 + wm*64 + 16*mi + 4*hi + rg;
          int c = col0 + wn*64 + lo + 16*ni;
          outp[(long)r*Ncols + c] = acc[mi][ni][rg];
        }
  } else {
    int wcol0 = col0 + wn*64;
    int region = (wcol0 < 896) ? 0 : (wcol0 < 1024) ? 1 : (wcol0 < 1152) ? 2 : 3;
    for(int mi=0;mi<4;mi++){
      for(int rg=0;rg<4;rg++){
        int r = row0 + wm*64 + 16*mi + 4*hi + rg;
        int b = r >> 11, n = r & 2047;
        if(region <= 1){
          // RoPE pair: acc[][ni] (d<32) with acc[][ni+2] (d+32), same head
          #pragma unroll
          for(int ni=0;ni<2;ni++){
            int c  = wcol0 + lo + 16*ni;
            int cb = (region==0) ? c : (c-896);
            int hh = cb >> 6, dlo = cb & 63;           // dlo < 32
            float bl = (region==0) ? bq[c]    : bk[cb];
            float bh = (region==0) ? bq[c+32] : bk[cb+32];
            float ylo = acc[mi][ni  ][rg] + bl;
            float yhi = acc[mi][ni+2][rg] + bh;
            float cs = ct[r*32 + dlo];
            float sn = st[r*32 + dlo];
            float olo = ylo*cs - yhi*sn;
            float ohi = yhi*cs + ylo*sn;
            if(region==0){
              long base = ((long)(b*NHQ + hh)*NSEQ + n)*HD;
              Qb[base + dlo]      = f2bf(olo);
              Qb[base + dlo + 32] = f2bf(ohi);
            } else {
              long base = ((long)(b*NHKV + hh)*NSEQ + n)*HD;
              Kb[base + dlo]      = f2bf(olo);
              Kb[base + dlo + 32] = f2bf(ohi);
            }
          }
        } else if(region == 2){
          #pragma unroll
          for(int ni=0;ni<4;ni++){
            int c = wcol0 + lo + 16*ni;
            int cv = c - 1024;
            int hh = cv >> 6, d = cv & 63;
            float y = acc[mi][ni][rg] + bv[cv];
            Vb[((long)(b*NHKV + hh)*NSEQ + n)*HD + d] = f2bf(y);
          }
        } else {
          #pragma unroll
          for(int ni=0;ni<4;ni++){
            int c = wcol0 + lo + 16*ni;
            int cg = c - 1152;
            float y = acc[mi][ni][rg];
            gateb[(long)r*NHID + cg] = f2bf(1.0f/(1.0f + __expf(-y)));
          }
        }
      }
    }
  }
}

// ---------------- fused causal GQA flash attention ----------------
// 1 wave / block, 32 q-rows / wave, 32x32x16 MFMA, zero LDS, zero barriers.
// Swapped QK^T: S^T = mfma(K, Q) -> col = q (lane&31), row = key (lane-local).
// PV uses a key-permutation applied to BOTH V^T A-frag addresses and P B-frags
// so P B-frags are pure in-register packs of the softmax output.

__global__ __launch_bounds__(64)
void attn2_kernel(const short* __restrict__ Qb, const short* __restrict__ Kb,
                  const short* __restrict__ VbT, const short* __restrict__ gateb,
                  short* __restrict__ Og)
{
  const float SC = 0.18033688011112042f;   // (1/8) * log2(e)
  int tid = threadIdx.x;
  int q5 = tid & 31, h = tid >> 5;

  // schedule: tt-major (t descending), 7 heads of same (b,kv,t) adjacent
  int bid = blockIdx.x;
  int hg = bid % 7;
  int rr = bid / 7;
  int bk = rr & 3;
  int tt = rr >> 2;
  int t  = 63 - tt;                 // 32-row q tile, large t first
  int b  = bk >> 1, kv = bk & 1;
  int hq = kv*7 + hg;
  int qg = t*32 + q5;

  const short* qrow = Qb + ((long)(b*NHQ + hq)*NSEQ + t*32 + q5)*HD;
  s16x8 qf[4];
  #pragma unroll
  for(int ks=0; ks<4; ++ks) qf[ks] = *(const s16x8*)(qrow + 16*ks + 8*h);

  const short* kbase = Kb  + (long)(b*NHKV + kv)*NSEQ*HD;
  const short* vbase = VbT + (long)(b*NHKV + kv)*HD*NSEQ;

  f32x16 oT[2];
  #pragma unroll
  for(int mt=0; mt<2; ++mt)
    #pragma unroll
    for(int rg=0; rg<16; ++rg) oT[mt][rg] = 0.f;
  float m = -__builtin_inff(), lsum = 0.f;
  int jmax = (t*32 + 31) >> 6;

  // preload K tile j=0: A-frag rows = key, k = d
  s16x8 kf[2][4];
  #pragma unroll
  for(int kt=0; kt<2; ++kt)
    #pragma unroll
    for(int ks=0; ks<4; ++ks)
      kf[kt][ks] = *(const s16x8*)(kbase + (long)(kt*32 + q5)*HD + 16*ks + 8*h);

  for(int j=0; j<=jmax; ++j){
    // V A-frags (permuted key order): elements e<4 at key 16s+4h+e, e>=4 at +8
    union V8 { s16x8 v8; s16x4 v4[2]; } vf[2][4];
    #pragma unroll
    for(int mt=0; mt<2; ++mt)
      #pragma unroll
      for(int s=0; s<4; ++s){
        const short* vp = vbase + (long)(mt*32 + q5)*NSEQ + j*64 + 16*s + 4*h;
        vf[mt][s].v4[0] = *(const s16x4*)(vp);
        vf[mt][s].v4[1] = *(const s16x4*)(vp + 8);
      }

    // S^T = K * Q^T  (M=key tile of 32, N=q=32, K-dim d=64 in 4 steps)
    f32x16 s2[2];
    #pragma unroll
    for(int kt=0; kt<2; ++kt)
      #pragma unroll
      for(int rg=0; rg<16; ++rg) s2[kt][rg] = 0.f;
    #pragma unroll
    for(int kt=0; kt<2; ++kt)
      #pragma unroll
      for(int ks=0; ks<4; ++ks)
        s2[kt] = __builtin_amdgcn_mfma_f32_32x32x16_bf16(kf[kt][ks], qf[ks], s2[kt], 0,0,0);

    // prefetch next K tile while softmax+PV run
    int jn = (j < jmax) ? j+1 : jmax;
    s16x8 kn[2][4];
    #pragma unroll
    for(int kt=0; kt<2; ++kt)
      #pragma unroll
      for(int ks=0; ks<4; ++ks)
        kn[kt][ks] = *(const s16x8*)(kbase + (long)(jn*64 + kt*32 + q5)*HD + 16*ks + 8*h);

    // scale (+ causal mask on diagonal tile). key row = (rg&3)+8*(rg>>2)+4h
    if(j == jmax){
      #pragma unroll
      for(int kt=0; kt<2; ++kt)
        #pragma unroll
        for(int rg=0; rg<16; ++rg){
          int kl = j*64 + kt*32 + (rg&3) + 8*(rg>>2) + 4*h;
          float sv = s2[kt][rg]*SC;
          s2[kt][rg] = (kl > qg) ? -__builtin_inff() : sv;
        }
    } else {
      #pragma unroll
      for(int kt=0; kt<2; ++kt)
        #pragma unroll
        for(int rg=0; rg<16; ++rg) s2[kt][rg] *= SC;
    }

    // row-max: 32 in-lane (tree) + 1 shuffle across h
    float mA[8];
    #pragma unroll
    for(int w8=0; w8<8; ++w8)
      mA[w8] = fmaxf(fmaxf(s2[0][w8], s2[0][w8+8]), fmaxf(s2[1][w8], s2[1][w8+8]));
    float mx = fmaxf(fmaxf(fmaxf(mA[0],mA[1]), fmaxf(mA[2],mA[3])),
                     fmaxf(fmaxf(mA[4],mA[5]), fmaxf(mA[6],mA[7])));
    mx = fmaxf(mx, __shfl_xor(mx, 32, 64));

    float mn  = fmaxf(m, mx);
    float fac = exp2f(m - mn);
    m = mn;

    // exp + row-sum (tree + 1 shuffle)
    #pragma unroll
    for(int kt=0; kt<2; ++kt)
      #pragma unroll
      for(int rg=0; rg<16; ++rg) s2[kt][rg] = exp2f(s2[kt][rg] - mn);
    float sA[8];
    #pragma unroll
    for(int w8=0; w8<8; ++w8)
      sA[w8] = (s2[0][w8] + s2[0][w8+8]) + (s2[1][w8] + s2[1][w8+8]);
    float rs = ((sA[0]+sA[1]) + (sA[2]+sA[3])) + ((sA[4]+sA[5]) + (sA[6]+sA[7]));
    rs += __shfl_xor(rs, 32, 64);

    lsum = lsum*fac + rs;
    #pragma unroll
    for(int mt=0; mt<2; ++mt)
      #pragma unroll
      for(int rg=0; rg<16; ++rg) oT[mt][rg] *= fac;

    // pack P to bf16 pairs: pd[kt][w] = {p[2w] lo, p[2w+1] hi}
    int pd[2][8];
    #pragma unroll
    for(int kt=0; kt<2; ++kt)
      #pragma unroll
      for(int w8=0; w8<8; ++w8)
        asm("v_cvt_pk_bf16_f32 %0, %1, %2"
            : "=v"(pd[kt][w8]) : "v"(s2[kt][2*w8]), "v"(s2[kt][2*w8+1]));

    // PV: O^T += V^T * P^T ; B-frag for step s = pd[s>>1][4*(s&1) .. +3]
    #pragma unroll
    for(int s=0; s<4; ++s){
      union { int i4[4]; s16x8 v8; } pf;
      #pragma unroll
      for(int e=0; e<4; ++e) pf.i4[e] = pd[s>>1][4*(s&1) + e];
      #pragma unroll
      for(int mt=0; mt<2; ++mt)
        oT[mt] = __builtin_amdgcn_mfma_f32_32x32x16_bf16(vf[mt][s].v8, pf.v8, oT[mt], 0,0,0);
    }

    // roll K prefetch
    #pragma unroll
    for(int kt=0; kt<2; ++kt)
      #pragma unroll
      for(int ks=0; ks<4; ++ks) kf[kt][ks] = kn[kt][ks];
  }

  float inv = 1.0f/lsum;
  long obase = ((long)(b*NSEQ + t*32 + q5))*NHID + hq*HD;
  #pragma unroll
  for(int mt=0; mt<2; ++mt)
    #pragma unroll
    for(int rq=0; rq<4; ++rq){
      int d0 = mt*32 + 8*rq + 4*h;
      s16x4 g4 = *(const s16x4*)(gateb + obase + d0);
      s16x4 o4;
      #pragma unroll
      for(int e=0; e<4; ++e)
        o4[e] = f2bf(oT[mt][4*rq + e]*inv*bf2f((unsigned short)g4[e]));
      *(s16x4*)(Og + obase + d0) = o4;
    }
}

// ---------------- launch ----------------

extern "C" void kernel_launch(void* const* d_in, const int* in_sizes, int n_in,
                              void* d_out, int out_size, void* d_ws, size_t ws_size,
                              hipStream_t stream)
{
  const float* hs  = (const float*)d_in[0];
  const int*   pos = (const int*)d_in[1];
  const float* Wq  = (const float*)d_in[2];
  const float* bq  = (const float*)d_in[3];
  const float* Wk  = (const float*)d_in[4];
  const float* bk  = (const float*)d_in[5];
  const float* Wv  = (const float*)d_in[6];
  const float* bv  = (const float*)d_in[7];
  const float* Wg  = (const float*)d_in[8];
  const float* Wo  = (const float*)d_in[9];
  float* out = (float*)d_out;

  char* p = (char*)d_ws;
  short* Xb    = (short*)p; p += (size_t)NROW*NHID*2;
  short* WcatT = (short*)p; p += (size_t)NCAT*NHID*2;
  short* WoT   = (short*)p; p += (size_t)NHID*NHID*2;
  float* ct    = (float*)p; p += (size_t)NROW*32*4;
  float* st    = (float*)p; p += (size_t)NROW*32*4;
  short* Qb    = (short*)p; p += (size_t)NB*NHQ*NSEQ*HD*2;
  short* Kb    = (short*)p; p += (size_t)NB*NHKV*NSEQ*HD*2;
  short* Vb    = (short*)p; p += (size_t)NB*NHKV*NSEQ*HD*2;
  short* VbT   = (short*)p; p += (size_t)NB*NHKV*NSEQ*HD*2;
  short* gateb = (short*)p; p += (size_t)NROW*NHID*2;
  short* Og    = (short*)p; p += (size_t)NROW*NHID*2;

  pack_x_kernel<<<(NROW*NHID+255)/256, 256, 0, stream>>>(hs, Xb, NROW*NHID);
  pack_wcat_kernel<<<(NCAT*NHID+255)/256, 256, 0, stream>>>(Wq, Wk, Wv, Wg, WcatT);
  pack_wo_kernel<<<(NHID*NHID+255)/256, 256, 0, stream>>>(Wo, WoT);
  rope_table_kernel<<<(NROW*32+255)/256, 256, 0, stream>>>(pos, ct, st);

  gemm_kernel<0><<<dim3(NCAT/128, NROW/128), 256, 0, stream>>>(
      Xb, WcatT, NCAT, NHID, bq, bk, bv, ct, st, Qb, Kb, Vb, gateb, nullptr);

  transpose_v_kernel<<<dim3(NSEQ/64, NB*NHKV), 256, 0, stream>>>(Vb, VbT);

  attn2_kernel<<<64*4*7, 64, 0, stream>>>(Qb, Kb, VbT, gateb, Og);

  gemm_kernel<1><<<dim3(NHID/128, NROW/128), 256, 0, stream>>>(
      Og, WoT, NHID, NHID, nullptr, nullptr, nullptr, nullptr, nullptr,
      nullptr, nullptr, nullptr, nullptr, out);
}

// Round 4
// 176.769 us; speedup vs baseline: 1.6852x; 1.6147x over previous
//
#include <hip/hip_runtime.h>
#include <hip/hip_bf16.h>

typedef short s16x4 __attribute__((ext_vector_type(4)));
typedef short s16x8 __attribute__((ext_vector_type(8)));
typedef float f32x4 __attribute__((ext_vector_type(4)));
typedef float f32x16 __attribute__((ext_vector_type(16)));

#define NB 2
#define NSEQ 2048
#define NHID 896
#define NHQ 14
#define NHKV 2
#define HD 64
#define NROW (NB*NSEQ)     // 4096
#define NCAT 2048          // 896 Q | 128 K | 128 V | 896 gate
#define PS 40              // padded LDS row stride in shorts (80B, 16B-aligned, <=2-way banks)

__device__ __forceinline__ float bf2f(unsigned short s){
  union { float f; unsigned u; } v; v.u = ((unsigned)s) << 16; return v.f;
}
__device__ __forceinline__ short f2bf(float f){
  union { float f; unsigned u; } v; v.f = f;
  unsigned u = v.u + 0x7fffu + ((v.u >> 16) & 1u);
  return (short)(u >> 16);
}

// ---------------- packing kernels ----------------

__global__ void pack_x_kernel(const float* __restrict__ x, short* __restrict__ xb, int n){
  int i = blockIdx.x*256 + threadIdx.x;
  if(i < n) xb[i] = f2bf(x[i]);
}

// WcatT[c][k] = W(k, c) for concatenated [Wq|Wk|Wv|Wg] columns, bf16
__global__ void pack_wcat_kernel(const float* __restrict__ Wq, const float* __restrict__ Wk,
                                 const float* __restrict__ Wv, const float* __restrict__ Wg,
                                 short* __restrict__ WcatT){
  int t = blockIdx.x*256 + threadIdx.x;
  if(t >= NCAT*NHID) return;
  int k = t % NHID, c = t / NHID;
  float v;
  if(c < 896)       v = Wq[k*896 + c];
  else if(c < 1024) v = Wk[k*128 + (c-896)];
  else if(c < 1152) v = Wv[k*128 + (c-1024)];
  else              v = Wg[k*896 + (c-1152)];
  WcatT[t] = f2bf(v);
}

__global__ void pack_wo_kernel(const float* __restrict__ Wo, short* __restrict__ WoT){
  int t = blockIdx.x*256 + threadIdx.x;
  if(t >= NHID*NHID) return;
  int k = t % NHID, c = t / NHID;
  WoT[t] = f2bf(Wo[k*896 + c]);
}

__global__ void rope_table_kernel(const int* __restrict__ pos, float* __restrict__ ct,
                                  float* __restrict__ st){
  int t = blockIdx.x*256 + threadIdx.x;
  if(t >= NROW*32) return;
  int i = t & 31, rn = t >> 5;
  float p = (float)pos[rn];
  float inv = powf(1.0e6f, -(float)i * (1.0f/32.0f));
  float a = p * inv;
  ct[t] = cosf(a);
  st[t] = sinf(a);
}

// V [bh][n][d] -> VbT [bh][d][n]  (LDS tiled transpose, bf16)
__global__ __launch_bounds__(256) void transpose_v_kernel(const short* __restrict__ Vb,
                                                          short* __restrict__ VbT){
  __shared__ short t[64][66];
  int bh = blockIdx.y;           // 0..3
  int n0 = blockIdx.x * 64;      // 32 tiles
  int tid = threadIdx.x;
  #pragma unroll
  for(int it=0; it<2; ++it){
    int idx = it*256 + tid;
    int r = idx >> 3, c0 = (idx & 7)*8;
    s16x8 v = *(const s16x8*)(Vb + ((long)bh*NSEQ + n0 + r)*HD + c0);
    #pragma unroll
    for(int e=0;e<8;e++) t[r][c0+e] = v[e];
  }
  __syncthreads();
  #pragma unroll
  for(int it=0; it<2; ++it){
    int idx = it*256 + tid;
    int d = idx >> 3, k0 = (idx & 7)*8;
    s16x8 o;
    #pragma unroll
    for(int e=0;e<8;e++) o[e] = t[k0+e][d];
    *(s16x8*)(VbT + ((long)bh*HD + d)*NSEQ + n0 + k0) = o;
  }
}

// ---------------- GEMM (bf16 MFMA, reg-staged LDS double-buffer) ----------------
// EPI=0: QKVG epilogue, EPI=1: plain f32 out
// NOTE: every loop touching acc[][] MUST be #pragma unroll'd — runtime index
// on an ext_vector array sends the whole array to scratch (rule #20).

template<int EPI>
__global__ __launch_bounds__(256)
void gemm_kernel(const short* __restrict__ A, const short* __restrict__ Bt,
                 int Ncols, int K,
                 const float* __restrict__ bq, const float* __restrict__ bk,
                 const float* __restrict__ bv,
                 const float* __restrict__ ct, const float* __restrict__ st,
                 short* __restrict__ Qb, short* __restrict__ Kb, short* __restrict__ Vb,
                 short* __restrict__ gateb, float* __restrict__ outp)
{
  __shared__ short As[2][128*PS];
  __shared__ short Bs[2][128*PS];

  int tid = threadIdx.x;
  int w = tid >> 6, l = tid & 63;
  int wm = w >> 1, wn = w & 1;
  int row0 = blockIdx.y*128;
  int col0 = blockIdx.x*128;
  int lo = l & 15, hi = l >> 4;

  const short* A0 = A  + (long)row0*K;
  const short* B0 = Bt + (long)col0*K;

  f32x4 acc[4][4];
  #pragma unroll
  for(int mi=0;mi<4;mi++)
    #pragma unroll
    for(int ni=0;ni<4;ni++) acc[mi][ni] = (f32x4){0.f,0.f,0.f,0.f};

  int srow = tid >> 2;          // 0..63
  int scol = (tid & 3)*8;       // 16B chunk within 32-k row

  s16x8 ra[2], rb[2];
  auto gload = [&](int k0){
    #pragma unroll
    for(int i=0;i<2;i++){
      int row = i*64 + srow;
      ra[i] = *(const s16x8*)(A0 + (long)row*K + k0 + scol);
      rb[i] = *(const s16x8*)(B0 + (long)row*K + k0 + scol);
    }
  };
  auto swrite = [&](int buf){
    #pragma unroll
    for(int i=0;i<2;i++){
      int row = i*64 + srow;
      *(s16x8*)&As[buf][row*PS + scol] = ra[i];
      *(s16x8*)&Bs[buf][row*PS + scol] = rb[i];
    }
  };

  gload(0);
  swrite(0);

  int NIT = K >> 5;
  int cur = 0;
  for(int it=0; it<NIT; ++it){
    __syncthreads();
    if(it+1 < NIT) gload((it+1)*32);

    s16x8 af[4], bf[4];
    #pragma unroll
    for(int mi=0;mi<4;mi++) af[mi] = *(const s16x8*)&As[cur][(wm*64 + 16*mi + lo)*PS + 8*hi];
    #pragma unroll
    for(int ni=0;ni<4;ni++) bf[ni] = *(const s16x8*)&Bs[cur][(wn*64 + 16*ni + lo)*PS + 8*hi];
    #pragma unroll
    for(int mi=0;mi<4;mi++)
      #pragma unroll
      for(int ni=0;ni<4;ni++)
        acc[mi][ni] = __builtin_amdgcn_mfma_f32_16x16x32_bf16(af[mi], bf[ni], acc[mi][ni], 0,0,0);

    if(it+1 < NIT) swrite(cur^1);
    cur ^= 1;
  }

  if(EPI == 1){
    #pragma unroll
    for(int mi=0;mi<4;mi++)
      #pragma unroll
      for(int ni=0;ni<4;ni++)
        #pragma unroll
        for(int rg=0;rg<4;rg++){
          int r = row0 + wm*64 + 16*mi + 4*hi + rg;
          int c = col0 + wn*64 + lo + 16*ni;
          outp[(long)r*Ncols + c] = acc[mi][ni][rg];
        }
  } else {
    int wcol0 = col0 + wn*64;
    int region = (wcol0 < 896) ? 0 : (wcol0 < 1024) ? 1 : (wcol0 < 1152) ? 2 : 3;
    #pragma unroll
    for(int mi=0;mi<4;mi++){
      #pragma unroll
      for(int rg=0;rg<4;rg++){
        int r = row0 + wm*64 + 16*mi + 4*hi + rg;
        int b = r >> 11, n = r & 2047;
        if(region <= 1){
          // RoPE pair: acc[][ni] (d<32) with acc[][ni+2] (d+32), same head
          #pragma unroll
          for(int ni=0;ni<2;ni++){
            int c  = wcol0 + lo + 16*ni;
            int cb = (region==0) ? c : (c-896);
            int hh = cb >> 6, dlo = cb & 63;           // dlo < 32
            float bl = (region==0) ? bq[c]    : bk[cb];
            float bh = (region==0) ? bq[c+32] : bk[cb+32];
            float ylo = acc[mi][ni  ][rg] + bl;
            float yhi = acc[mi][ni+2][rg] + bh;
            float cs = ct[r*32 + dlo];
            float sn = st[r*32 + dlo];
            float olo = ylo*cs - yhi*sn;
            float ohi = yhi*cs + ylo*sn;
            if(region==0){
              long base = ((long)(b*NHQ + hh)*NSEQ + n)*HD;
              Qb[base + dlo]      = f2bf(olo);
              Qb[base + dlo + 32] = f2bf(ohi);
            } else {
              long base = ((long)(b*NHKV + hh)*NSEQ + n)*HD;
              Kb[base + dlo]      = f2bf(olo);
              Kb[base + dlo + 32] = f2bf(ohi);
            }
          }
        } else if(region == 2){
          #pragma unroll
          for(int ni=0;ni<4;ni++){
            int c = wcol0 + lo + 16*ni;
            int cv = c - 1024;
            int hh = cv >> 6, d = cv & 63;
            float y = acc[mi][ni][rg] + bv[cv];
            Vb[((long)(b*NHKV + hh)*NSEQ + n)*HD + d] = f2bf(y);
          }
        } else {
          #pragma unroll
          for(int ni=0;ni<4;ni++){
            int c = wcol0 + lo + 16*ni;
            int cg = c - 1152;
            float y = acc[mi][ni][rg];
            gateb[(long)r*NHID + cg] = f2bf(1.0f/(1.0f + __expf(-y)));
          }
        }
      }
    }
  }
}

// ---------------- fused causal GQA flash attention ----------------
// 1 wave / block, 32 q-rows / wave, 32x32x16 MFMA, zero LDS, zero barriers.
// Swapped QK^T: S^T = mfma(K, Q) -> col = q (lane&31), row = key (lane-local).
// PV uses a key-permutation applied to BOTH V^T A-frag addresses and P B-frags
// so P B-frags are pure in-register packs of the softmax output.

__global__ __launch_bounds__(64)
void attn2_kernel(const short* __restrict__ Qb, const short* __restrict__ Kb,
                  const short* __restrict__ VbT, const short* __restrict__ gateb,
                  short* __restrict__ Og)
{
  const float SC = 0.18033688011112042f;   // (1/8) * log2(e)
  int tid = threadIdx.x;
  int q5 = tid & 31, h = tid >> 5;

  // schedule: tt-major (t descending), 7 heads of same (b,kv,t) adjacent
  int bid = blockIdx.x;
  int hg = bid % 7;
  int rr = bid / 7;
  int bk = rr & 3;
  int tt = rr >> 2;
  int t  = 63 - tt;                 // 32-row q tile, large t first
  int b  = bk >> 1, kv = bk & 1;
  int hq = kv*7 + hg;
  int qg = t*32 + q5;

  const short* qrow = Qb + ((long)(b*NHQ + hq)*NSEQ + t*32 + q5)*HD;
  s16x8 qf[4];
  #pragma unroll
  for(int ks=0; ks<4; ++ks) qf[ks] = *(const s16x8*)(qrow + 16*ks + 8*h);

  const short* kbase = Kb  + (long)(b*NHKV + kv)*NSEQ*HD;
  const short* vbase = VbT + (long)(b*NHKV + kv)*HD*NSEQ;

  f32x16 oT[2];
  #pragma unroll
  for(int mt=0; mt<2; ++mt)
    #pragma unroll
    for(int rg=0; rg<16; ++rg) oT[mt][rg] = 0.f;
  float m = -__builtin_inff(), lsum = 0.f;
  int jmax = (t*32 + 31) >> 6;

  // preload K tile j=0: A-frag rows = key, k = d
  s16x8 kf[2][4];
  #pragma unroll
  for(int kt=0; kt<2; ++kt)
    #pragma unroll
    for(int ks=0; ks<4; ++ks)
      kf[kt][ks] = *(const s16x8*)(kbase + (long)(kt*32 + q5)*HD + 16*ks + 8*h);

  for(int j=0; j<=jmax; ++j){
    // V A-frags (permuted key order): elements e<4 at key 16s+4h+e, e>=4 at +8
    union V8 { s16x8 v8; s16x4 v4[2]; } vf[2][4];
    #pragma unroll
    for(int mt=0; mt<2; ++mt)
      #pragma unroll
      for(int s=0; s<4; ++s){
        const short* vp = vbase + (long)(mt*32 + q5)*NSEQ + j*64 + 16*s + 4*h;
        vf[mt][s].v4[0] = *(const s16x4*)(vp);
        vf[mt][s].v4[1] = *(const s16x4*)(vp + 8);
      }

    // S^T = K * Q^T  (M=key tile of 32, N=q=32, K-dim d=64 in 4 steps)
    f32x16 s2[2];
    #pragma unroll
    for(int kt=0; kt<2; ++kt)
      #pragma unroll
      for(int rg=0; rg<16; ++rg) s2[kt][rg] = 0.f;
    #pragma unroll
    for(int kt=0; kt<2; ++kt)
      #pragma unroll
      for(int ks=0; ks<4; ++ks)
        s2[kt] = __builtin_amdgcn_mfma_f32_32x32x16_bf16(kf[kt][ks], qf[ks], s2[kt], 0,0,0);

    // prefetch next K tile while softmax+PV run
    int jn = (j < jmax) ? j+1 : jmax;
    s16x8 kn[2][4];
    #pragma unroll
    for(int kt=0; kt<2; ++kt)
      #pragma unroll
      for(int ks=0; ks<4; ++ks)
        kn[kt][ks] = *(const s16x8*)(kbase + (long)(jn*64 + kt*32 + q5)*HD + 16*ks + 8*h);

    // scale (+ causal mask on diagonal tile). key row = (rg&3)+8*(rg>>2)+4h
    if(j == jmax){
      #pragma unroll
      for(int kt=0; kt<2; ++kt)
        #pragma unroll
        for(int rg=0; rg<16; ++rg){
          int kl = j*64 + kt*32 + (rg&3) + 8*(rg>>2) + 4*h;
          float sv = s2[kt][rg]*SC;
          s2[kt][rg] = (kl > qg) ? -__builtin_inff() : sv;
        }
    } else {
      #pragma unroll
      for(int kt=0; kt<2; ++kt)
        #pragma unroll
        for(int rg=0; rg<16; ++rg) s2[kt][rg] *= SC;
    }

    // row-max: 32 in-lane (tree) + 1 shuffle across h
    float mA[8];
    #pragma unroll
    for(int w8=0; w8<8; ++w8)
      mA[w8] = fmaxf(fmaxf(s2[0][w8], s2[0][w8+8]), fmaxf(s2[1][w8], s2[1][w8+8]));
    float mx = fmaxf(fmaxf(fmaxf(mA[0],mA[1]), fmaxf(mA[2],mA[3])),
                     fmaxf(fmaxf(mA[4],mA[5]), fmaxf(mA[6],mA[7])));
    mx = fmaxf(mx, __shfl_xor(mx, 32, 64));

    float mn  = fmaxf(m, mx);
    float fac = exp2f(m - mn);
    m = mn;

    // exp + row-sum (tree + 1 shuffle)
    #pragma unroll
    for(int kt=0; kt<2; ++kt)
      #pragma unroll
      for(int rg=0; rg<16; ++rg) s2[kt][rg] = exp2f(s2[kt][rg] - mn);
    float sA[8];
    #pragma unroll
    for(int w8=0; w8<8; ++w8)
      sA[w8] = (s2[0][w8] + s2[0][w8+8]) + (s2[1][w8] + s2[1][w8+8]);
    float rs = ((sA[0]+sA[1]) + (sA[2]+sA[3])) + ((sA[4]+sA[5]) + (sA[6]+sA[7]));
    rs += __shfl_xor(rs, 32, 64);

    lsum = lsum*fac + rs;
    #pragma unroll
    for(int mt=0; mt<2; ++mt)
      #pragma unroll
      for(int rg=0; rg<16; ++rg) oT[mt][rg] *= fac;

    // pack P to bf16 pairs: pd[kt][w] = {p[2w] lo, p[2w+1] hi}
    int pd[2][8];
    #pragma unroll
    for(int kt=0; kt<2; ++kt)
      #pragma unroll
      for(int w8=0; w8<8; ++w8)
        asm("v_cvt_pk_bf16_f32 %0, %1, %2"
            : "=v"(pd[kt][w8]) : "v"(s2[kt][2*w8]), "v"(s2[kt][2*w8+1]));

    // PV: O^T += V^T * P^T ; B-frag for step s = pd[s>>1][4*(s&1) .. +3]
    #pragma unroll
    for(int s=0; s<4; ++s){
      union { int i4[4]; s16x8 v8; } pf;
      #pragma unroll
      for(int e=0; e<4; ++e) pf.i4[e] = pd[s>>1][4*(s&1) + e];
      #pragma unroll
      for(int mt=0; mt<2; ++mt)
        oT[mt] = __builtin_amdgcn_mfma_f32_32x32x16_bf16(vf[mt][s].v8, pf.v8, oT[mt], 0,0,0);
    }

    // roll K prefetch
    #pragma unroll
    for(int kt=0; kt<2; ++kt)
      #pragma unroll
      for(int ks=0; ks<4; ++ks) kf[kt][ks] = kn[kt][ks];
  }

  float inv = 1.0f/lsum;
  long obase = ((long)(b*NSEQ + t*32 + q5))*NHID + hq*HD;
  #pragma unroll
  for(int mt=0; mt<2; ++mt)
    #pragma unroll
    for(int rq=0; rq<4; ++rq){
      int d0 = mt*32 + 8*rq + 4*h;
      s16x4 g4 = *(const s16x4*)(gateb + obase + d0);
      s16x4 o4;
      #pragma unroll
      for(int e=0; e<4; ++e)
        o4[e] = f2bf(oT[mt][4*rq + e]*inv*bf2f((unsigned short)g4[e]));
      *(s16x4*)(Og + obase + d0) = o4;
    }
}

// ---------------- launch ----------------

extern "C" void kernel_launch(void* const* d_in, const int* in_sizes, int n_in,
                              void* d_out, int out_size, void* d_ws, size_t ws_size,
                              hipStream_t stream)
{
  const float* hs  = (const float*)d_in[0];
  const int*   pos = (const int*)d_in[1];
  const float* Wq  = (const float*)d_in[2];
  const float* bq  = (const float*)d_in[3];
  const float* Wk  = (const float*)d_in[4];
  const float* bk  = (const float*)d_in[5];
  const float* Wv  = (const float*)d_in[6];
  const float* bv  = (const float*)d_in[7];
  const float* Wg  = (const float*)d_in[8];
  const float* Wo  = (const float*)d_in[9];
  float* out = (float*)d_out;

  char* p = (char*)d_ws;
  short* Xb    = (short*)p; p += (size_t)NROW*NHID*2;
  short* WcatT = (short*)p; p += (size_t)NCAT*NHID*2;
  short* WoT   = (short*)p; p += (size_t)NHID*NHID*2;
  float* ct    = (float*)p; p += (size_t)NROW*32*4;
  float* st    = (float*)p; p += (size_t)NROW*32*4;
  short* Qb    = (short*)p; p += (size_t)NB*NHQ*NSEQ*HD*2;
  short* Kb    = (short*)p; p += (size_t)NB*NHKV*NSEQ*HD*2;
  short* Vb    = (short*)p; p += (size_t)NB*NHKV*NSEQ*HD*2;
  short* VbT   = (short*)p; p += (size_t)NB*NHKV*NSEQ*HD*2;
  short* gateb = (short*)p; p += (size_t)NROW*NHID*2;
  short* Og    = (short*)p; p += (size_t)NROW*NHID*2;

  pack_x_kernel<<<(NROW*NHID+255)/256, 256, 0, stream>>>(hs, Xb, NROW*NHID);
  pack_wcat_kernel<<<(NCAT*NHID+255)/256, 256, 0, stream>>>(Wq, Wk, Wv, Wg, WcatT);
  pack_wo_kernel<<<(NHID*NHID+255)/256, 256, 0, stream>>>(Wo, WoT);
  rope_table_kernel<<<(NROW*32+255)/256, 256, 0, stream>>>(pos, ct, st);

  gemm_kernel<0><<<dim3(NCAT/128, NROW/128), 256, 0, stream>>>(
      Xb, WcatT, NCAT, NHID, bq, bk, bv, ct, st, Qb, Kb, Vb, gateb, nullptr);

  transpose_v_kernel<<<dim3(NSEQ/64, NB*NHKV), 256, 0, stream>>>(Vb, VbT);

  attn2_kernel<<<64*4*7, 64, 0, stream>>>(Qb, Kb, VbT, gateb, Og);

  gemm_kernel<1><<<dim3(NHID/128, NROW/128), 256, 0, stream>>>(
      Og, WoT, NHID, NHID, nullptr, nullptr, nullptr, nullptr, nullptr,
      nullptr, nullptr, nullptr, nullptr, out);
}